// Round 4
// baseline (1650.326 us; speedup 1.0000x reference)
//
#include <hip/hip_runtime.h>

// ---------------------------------------------------------------------------
// GraphSAGE 2-layer forward.
//   CSR build -> mean-agg(x) [bf16 m1] -> FUSED MLP:
//     h = relu([m1|x]@[W1l;W1r]+b1)   (h tile kept in LDS only)
//     g = h@W2l (bf16 ws), r = h@W2r (fp32 -> d_out)
//   -> agg(g)*dinv + r + b2 -> log_softmax (fused, wave-per-row)
// Layer-2 agg moved AFTER projection: segment_sum(h[src])@W2l ==
// segment_sum((h@W2l)[src]) -- aggregates 64 dims instead of 256.
// bf16 via explicit bit-ops (ROCm header helpers are version-fragile).
// ---------------------------------------------------------------------------

typedef unsigned short bf16_t;

static __device__ __forceinline__ bf16_t f2bf(float f) {
    unsigned u = __float_as_uint(f);
    u += 0x7FFFu + ((u >> 16) & 1u);   // round-to-nearest-even
    return (bf16_t)(u >> 16);
}
static __device__ __forceinline__ float bf2f(bf16_t h) {
    return __uint_as_float(((unsigned)h) << 16);
}

__global__ void k_hist(const int* __restrict__ ei, int E, int n, int* __restrict__ deg) {
    int e = blockIdx.x * 256 + threadIdx.x;
    if (e < E) {
        unsigned dst = (unsigned)ei[(size_t)E + e];
        if (dst < (unsigned)n) atomicAdd(&deg[dst], 1);
    }
}

__global__ void k_scan1(const int* __restrict__ deg, int n,
                        int* __restrict__ rs, int* __restrict__ bs) {
    __shared__ int sm[256];
    int i = blockIdx.x * 256 + threadIdx.x;
    int v = (i < n) ? deg[i] : 0;
    sm[threadIdx.x] = v;
    __syncthreads();
    for (int off = 1; off < 256; off <<= 1) {
        int t = (threadIdx.x >= off) ? sm[threadIdx.x - off] : 0;
        __syncthreads();
        sm[threadIdx.x] += t;
        __syncthreads();
    }
    if (i < n) rs[i] = sm[threadIdx.x] - v;   // exclusive within block
    if (threadIdx.x == 255) bs[blockIdx.x] = sm[255];
}

// exclusive scan of per-block sums (nb <= 1024), one block of 1024 threads
__global__ void k_scan2(int* bs, int nb) {
    __shared__ int sm[1024];
    int i = threadIdx.x;
    int v = (i < nb) ? bs[i] : 0;
    sm[i] = v;
    __syncthreads();
#pragma unroll 10
    for (int off = 1; off < 1024; off <<= 1) {
        int t = (i >= off) ? sm[i - off] : 0;
        __syncthreads();
        sm[i] += t;
        __syncthreads();
    }
    if (i < nb) bs[i] = sm[i] - v;
}

__global__ void k_scan3(const int* __restrict__ deg, const int* __restrict__ bs, int n,
                        int* __restrict__ rs, int* __restrict__ cur, float* __restrict__ dinv) {
    int i = blockIdx.x * 256 + threadIdx.x;
    if (i < n) {
        int v = rs[i] + bs[blockIdx.x];
        rs[i] = v;
        cur[i] = v;
        dinv[i] = 1.0f / fmaxf((float)deg[i], 1.0f);
    }
}

__global__ void k_fill(const int* __restrict__ ei, int E, int n,
                       int* __restrict__ cur, int* __restrict__ sorted) {
    int e = blockIdx.x * 256 + threadIdx.x;
    if (e < E) {
        unsigned src = (unsigned)ei[e];
        unsigned dst = (unsigned)ei[(size_t)E + e];
        if (dst < (unsigned)n && src < (unsigned)n) {
            int pos = atomicAdd(&cur[dst], 1);
            sorted[pos] = (int)src;
        }
    }
}

// mean-aggregate x (128 dims): one 64-lane wave per node, float2 per lane, bf16 out.
__global__ void k_agg1(const float* __restrict__ x, const int* __restrict__ rs,
                       const int* __restrict__ deg, const float* __restrict__ dinv,
                       const int* __restrict__ sorted, int n, bf16_t* __restrict__ m1) {
    int gw = (blockIdx.x * 256 + threadIdx.x) >> 6;
    int lane = threadIdx.x & 63;
    if (gw >= n) return;
    int s = rs[gw], d = deg[gw];
    float a0 = 0.f, a1 = 0.f;
    int j = 0;
    for (; j + 4 <= d; j += 4) {   // 4 independent row loads in flight
        int s0 = sorted[s + j], s1 = sorted[s + j + 1];
        int s2 = sorted[s + j + 2], s3 = sorted[s + j + 3];
        float2 v0 = *(const float2*)&x[(size_t)s0 * 128 + lane * 2];
        float2 v1 = *(const float2*)&x[(size_t)s1 * 128 + lane * 2];
        float2 v2 = *(const float2*)&x[(size_t)s2 * 128 + lane * 2];
        float2 v3 = *(const float2*)&x[(size_t)s3 * 128 + lane * 2];
        a0 += v0.x + v1.x + v2.x + v3.x;
        a1 += v0.y + v1.y + v2.y + v3.y;
    }
    for (; j < d; ++j) {
        int sp = sorted[s + j];
        float2 v = *(const float2*)&x[(size_t)sp * 128 + lane * 2];
        a0 += v.x; a1 += v.y;
    }
    float dv = dinv[gw];
    unsigned packed = ((unsigned)f2bf(a1 * dv) << 16) | (unsigned)f2bf(a0 * dv);
    ((unsigned*)m1)[(size_t)gw * 64 + lane] = packed;
}

// Fused MLP over a 32-row tile. Phase A: h^T tile (256x32) into LDS.
// Phase B: g = h@W2l (bf16), r = h@W2r (fp32 -> d_out).
__global__ __launch_bounds__(256) void k_fused_mlp(
    const bf16_t* __restrict__ m1, const float* __restrict__ x,
    const float* __restrict__ W1l, const float* __restrict__ W1r,
    const float* __restrict__ b1,
    const float* __restrict__ W2l, const float* __restrict__ W2r,
    bf16_t* __restrict__ g, float* __restrict__ r_out, int n) {
    __shared__ float hs[256][33];                 // hs[k][row] = h[row][k]
    __shared__ float stage[32 * 256 + 32 * 33];   // phase A: Bs + As; phase B: Bs2 aliases
    float* Bs = stage;                            // [32][256]
    float* As = stage + 32 * 256;                 // [32][33]

    int tid = threadIdx.x;
    int brow = blockIdx.x * 32;
    int rg = tid >> 5, cg = tid & 31;

    // ---- phase A: h[32][256] = relu([m1|x]@[W1l;W1r] + b1) ----
    float acc[4][8];
#pragma unroll
    for (int i = 0; i < 4; ++i)
#pragma unroll
        for (int j = 0; j < 8; ++j) acc[i][j] = 0.f;

    for (int k0 = 0; k0 < 256; k0 += 32) {
#pragma unroll
        for (int i = 0; i < 4; ++i) {             // As: 32x32 tile of [m1|x]
            int l = tid + 256 * i;
            int r = l >> 5, kl = l & 31;
            int row = brow + r, ka = k0 + kl;
            float v = 0.f;
            if (row < n)
                v = (ka < 128) ? bf2f(m1[(size_t)row * 128 + ka])
                               : x[(size_t)row * 128 + (ka - 128)];
            As[kl * 33 + r] = v;
        }
#pragma unroll
        for (int i = 0; i < 32; ++i) {            // Bs: 32x256 of [W1l;W1r]
            int l = tid + 256 * i;
            int kl = l >> 8, c = l & 255;
            int ka = k0 + kl;
            Bs[kl * 256 + c] = (ka < 128) ? W1l[(size_t)ka * 256 + c]
                                          : W1r[(size_t)(ka - 128) * 256 + c];
        }
        __syncthreads();
#pragma unroll
        for (int kl = 0; kl < 32; ++kl) {
            float a[4], b[8];
#pragma unroll
            for (int i = 0; i < 4; ++i) a[i] = As[kl * 33 + rg * 4 + i];
#pragma unroll
            for (int jj = 0; jj < 8; ++jj) b[jj] = Bs[kl * 256 + cg + 32 * jj];
#pragma unroll
            for (int i = 0; i < 4; ++i)
#pragma unroll
                for (int jj = 0; jj < 8; ++jj) acc[i][jj] += a[i] * b[jj];
        }
        __syncthreads();
    }
    // write h tile (transposed) to LDS with bias+relu
#pragma unroll
    for (int i = 0; i < 4; ++i)
#pragma unroll
        for (int jj = 0; jj < 8; ++jj) {
            int c = cg + 32 * jj;
            float v = acc[i][jj] + b1[c];
            hs[c][rg * 4 + i] = v > 0.f ? v : 0.f;
        }
    __syncthreads();

    // ---- phase B: [g|r][32][128] = h @ [W2l|W2r] ----
    float acc2[4][4];
#pragma unroll
    for (int i = 0; i < 4; ++i)
#pragma unroll
        for (int j = 0; j < 4; ++j) acc2[i][j] = 0.f;

    for (int k0 = 0; k0 < 256; k0 += 32) {
#pragma unroll
        for (int i = 0; i < 16; ++i) {            // Bs2: 32x128 of [W2l|W2r]
            int l = tid + 256 * i;
            int kl = l >> 7, c = l & 127;
            int ka = k0 + kl;
            Bs[kl * 128 + c] = (c < 64) ? W2l[(size_t)ka * 64 + c]
                                        : W2r[(size_t)ka * 64 + (c - 64)];
        }
        __syncthreads();
#pragma unroll
        for (int kl = 0; kl < 32; ++kl) {
            float a[4], b[4];
#pragma unroll
            for (int i = 0; i < 4; ++i) a[i] = hs[k0 + kl][rg * 4 + i];
#pragma unroll
            for (int jj = 0; jj < 4; ++jj) b[jj] = Bs[kl * 128 + cg + 32 * jj];
#pragma unroll
            for (int i = 0; i < 4; ++i)
#pragma unroll
                for (int jj = 0; jj < 4; ++jj) acc2[i][jj] += a[i] * b[jj];
        }
        __syncthreads();
    }
#pragma unroll
    for (int i = 0; i < 4; ++i) {
        int row = brow + rg * 4 + i;
        if (row < n) {
#pragma unroll
            for (int jj = 0; jj < 4; ++jj) {
                int c = cg + 32 * jj;
                if (c < 64) g[(size_t)row * 64 + c] = f2bf(acc2[i][jj]);
                else        r_out[(size_t)row * 64 + (c - 64)] = acc2[i][jj];
            }
        }
    }
}

// mean-aggregate g (64 dims, bf16) + r + b2 + log_softmax. One wave per node; lane = col.
__global__ void k_agg2_final(const bf16_t* __restrict__ g, const int* __restrict__ rs,
                             const int* __restrict__ deg, const float* __restrict__ dinv,
                             const int* __restrict__ sorted, const float* __restrict__ b2,
                             int n, float* __restrict__ out) {
    int gw = (blockIdx.x * 256 + threadIdx.x) >> 6;
    int lane = threadIdx.x & 63;
    if (gw >= n) return;
    int s = rs[gw], d = deg[gw];
    float a = 0.f;
    int j = 0;
    for (; j + 4 <= d; j += 4) {
        int s0 = sorted[s + j], s1 = sorted[s + j + 1];
        int s2 = sorted[s + j + 2], s3 = sorted[s + j + 3];
        a += bf2f(g[(size_t)s0 * 64 + lane]) + bf2f(g[(size_t)s1 * 64 + lane])
           + bf2f(g[(size_t)s2 * 64 + lane]) + bf2f(g[(size_t)s3 * 64 + lane]);
    }
    for (; j < d; ++j) a += bf2f(g[(size_t)sorted[s + j] * 64 + lane]);

    float o = a * dinv[gw] + out[(size_t)gw * 64 + lane] + b2[lane];
    float m = o;
#pragma unroll
    for (int off = 1; off < 64; off <<= 1) m = fmaxf(m, __shfl_xor(m, off));
    float p = expf(o - m);
    float ssum = p;
#pragma unroll
    for (int off = 1; off < 64; off <<= 1) ssum += __shfl_xor(ssum, off);
    out[(size_t)gw * 64 + lane] = (o - m) - logf(ssum);
}

extern "C" void kernel_launch(void* const* d_in, const int* in_sizes, int n_in,
                              void* d_out, int out_size, void* d_ws, size_t ws_size,
                              hipStream_t stream) {
    const float* x   = (const float*)d_in[0];
    const int*   ei  = (const int*)d_in[1];      // int32 per harness contract
    const float* W1l = (const float*)d_in[2];
    const float* W1r = (const float*)d_in[3];
    const float* b1  = (const float*)d_in[4];
    const float* W2l = (const float*)d_in[5];
    const float* W2r = (const float*)d_in[6];
    const float* b2  = (const float*)d_in[7];
    float* out = (float*)d_out;

    const int N = in_sizes[0] / 128;
    const int E = in_sizes[1] / 2;

    // workspace layout (~46.4 MB total; all offsets 4B-aligned)
    char* ws = (char*)d_ws;
    size_t off = 0;
    int*   deg    = (int*)(ws + off);   off += (size_t)N * 4;
    int*   rs     = (int*)(ws + off);   off += (size_t)N * 4;
    int*   cur    = (int*)(ws + off);   off += (size_t)N * 4;
    float* dinv   = (float*)(ws + off); off += (size_t)N * 4;
    int*   bs     = (int*)(ws + off);   off += 16384;
    int*   sorted = (int*)(ws + off);   off += (size_t)E * 4;
    bf16_t* m1 = (bf16_t*)(ws + off);   off += (size_t)N * 128 * 2;
    bf16_t* g  = (bf16_t*)(ws + off);   off += (size_t)N * 64 * 2;

    (void)hipMemsetAsync(deg, 0, (size_t)N * 4, stream);

    const int nb = (N + 255) / 256;   // 391 <= 1024
    k_hist <<<(E + 255) / 256, 256, 0, stream>>>(ei, E, N, deg);
    k_scan1<<<nb, 256, 0, stream>>>(deg, N, rs, bs);
    k_scan2<<<1, 1024, 0, stream>>>(bs, nb);
    k_scan3<<<nb, 256, 0, stream>>>(deg, bs, N, rs, cur, dinv);
    k_fill <<<(E + 255) / 256, 256, 0, stream>>>(ei, E, N, cur, sorted);

    k_agg1 <<<(N * 64 + 255) / 256, 256, 0, stream>>>(x, rs, deg, dinv, sorted, N, m1);
    k_fused_mlp<<<(N + 31) / 32, 256, 0, stream>>>(m1, x, W1l, W1r, b1, W2l, W2r, g, out, N);
    k_agg2_final<<<(N * 64 + 255) / 256, 256, 0, stream>>>(g, rs, deg, dinv, sorted, b2, N, out);
}

// Round 5
// 622.636 us; speedup vs baseline: 2.6505x; 2.6505x over previous
//
#include <hip/hip_runtime.h>

// ---------------------------------------------------------------------------
// GraphSAGE 2-layer forward, MFMA edition.
//   CSR build -> cast x->bf16 into a2[N][256] (cols 128..255)
//   -> mean-agg(x) writes m1 into a2 (cols 0..127)
//   -> prep weights: Wc1[256][256], Wc2[128][256] bf16, transposed to [out][k]
//   -> k_mlp (MFMA 16x16x32 bf16):
//        phase A: h[64][256] = relu(a2 @ Wc1^T + b1)  (h -> LDS, bf16)
//        phase B: g = h@W2l -> a2 cols 0..63 ; r = h@W2r -> d_out (fp32)
//   -> agg(g)*dinv + r + b2 -> log_softmax (wave per node)
// Layer-2 agg after projection: segment_sum(h[src])@W2l == segment_sum((h@W2l)[src]).
// MFMA frags: A/B lane l holds M[l&15][(l>>4)*8+j]; D: col=lane&15, row=(lane>>4)*4+reg.
// ---------------------------------------------------------------------------

typedef unsigned short bf16_t;
typedef __attribute__((ext_vector_type(8))) short short8;
typedef __attribute__((ext_vector_type(4))) float f32x4;

static __device__ __forceinline__ bf16_t f2bf(float f) {
    unsigned u = __float_as_uint(f);
    u += 0x7FFFu + ((u >> 16) & 1u);   // round-to-nearest-even
    return (bf16_t)(u >> 16);
}
static __device__ __forceinline__ float bf2f(bf16_t h) {
    return __uint_as_float(((unsigned)h) << 16);
}
static __device__ __forceinline__ unsigned pack2(float lo, float hi) {
    return ((unsigned)f2bf(hi) << 16) | (unsigned)f2bf(lo);
}

// ---------------- CSR build ----------------
__global__ void k_hist(const int* __restrict__ ei, int E, int n, int* __restrict__ deg) {
    int e = blockIdx.x * 256 + threadIdx.x;
    if (e < E) {
        unsigned dst = (unsigned)ei[(size_t)E + e];
        if (dst < (unsigned)n) atomicAdd(&deg[dst], 1);
    }
}

__global__ void k_scan1(const int* __restrict__ deg, int n,
                        int* __restrict__ rs, int* __restrict__ bs) {
    __shared__ int sm[256];
    int i = blockIdx.x * 256 + threadIdx.x;
    int v = (i < n) ? deg[i] : 0;
    sm[threadIdx.x] = v;
    __syncthreads();
    for (int off = 1; off < 256; off <<= 1) {
        int t = (threadIdx.x >= off) ? sm[threadIdx.x - off] : 0;
        __syncthreads();
        sm[threadIdx.x] += t;
        __syncthreads();
    }
    if (i < n) rs[i] = sm[threadIdx.x] - v;
    if (threadIdx.x == 255) bs[blockIdx.x] = sm[255];
}

__global__ void k_scan2(int* bs, int nb) {
    __shared__ int sm[1024];
    int i = threadIdx.x;
    int v = (i < nb) ? bs[i] : 0;
    sm[i] = v;
    __syncthreads();
    for (int off = 1; off < 1024; off <<= 1) {
        int t = (i >= off) ? sm[i - off] : 0;
        __syncthreads();
        sm[i] += t;
        __syncthreads();
    }
    if (i < nb) bs[i] = sm[i] - v;
}

__global__ void k_scan3(const int* __restrict__ deg, const int* __restrict__ bs, int n,
                        int* __restrict__ rs, int* __restrict__ cur, float* __restrict__ dinv) {
    int i = blockIdx.x * 256 + threadIdx.x;
    if (i < n) {
        int v = rs[i] + bs[blockIdx.x];
        rs[i] = v;
        cur[i] = v;
        dinv[i] = 1.0f / fmaxf((float)deg[i], 1.0f);
    }
}

__global__ void k_fill(const int* __restrict__ ei, int E, int n,
                       int* __restrict__ cur, int* __restrict__ sorted) {
    int e = blockIdx.x * 256 + threadIdx.x;
    if (e < E) {
        unsigned src = (unsigned)ei[e];
        unsigned dst = (unsigned)ei[(size_t)E + e];
        if (dst < (unsigned)n && src < (unsigned)n) {
            int pos = atomicAdd(&cur[dst], 1);
            sorted[pos] = (int)src;
        }
    }
}

// ---------------- dtype prep ----------------
// x fp32 -> bf16x2 into a2 cols 128..255 (uint view: row*128 + 64 + c2)
__global__ void k_cast(const float* __restrict__ x, unsigned* __restrict__ a2u, int n) {
    int i = blockIdx.x * 256 + threadIdx.x;
    if (i < n * 64) {
        int row = i >> 6, c2 = i & 63;
        float2 v = *(const float2*)&x[(size_t)row * 128 + c2 * 2];
        a2u[(size_t)row * 128 + 64 + c2] = pack2(v.x, v.y);
    }
}

// Wc1[o][k] = bf16(k<128 ? W1l[k][o] : W1r[k-128][o]),  o<256, k<256
__global__ void k_prepw1(const float* __restrict__ W1l, const float* __restrict__ W1r,
                         bf16_t* __restrict__ Wc1) {
    int t = blockIdx.x * 256 + threadIdx.x;   // 65536
    int o = t >> 8, k = t & 255;
    float v = (k < 128) ? W1l[(size_t)k * 256 + o] : W1r[(size_t)(k - 128) * 256 + o];
    Wc1[t] = f2bf(v);
}

// Wc2[o][k] = bf16(o<64 ? W2l[k][o] : W2r[k][o-64]),  o<128, k<256
__global__ void k_prepw2(const float* __restrict__ W2l, const float* __restrict__ W2r,
                         bf16_t* __restrict__ Wc2) {
    int t = blockIdx.x * 256 + threadIdx.x;   // 32768
    int o = t >> 8, k = t & 255;
    float v = (o < 64) ? W2l[(size_t)k * 64 + o] : W2r[(size_t)k * 64 + (o - 64)];
    Wc2[t] = f2bf(v);
}

// ---------------- aggregation 1 ----------------
// gather bf16 x-halves of a2, mean, write m1 (bf16) into a2 cols 0..127.
__global__ void k_agg1(unsigned* __restrict__ a2u, const int* __restrict__ rs,
                       const int* __restrict__ deg, const float* __restrict__ dinv,
                       const int* __restrict__ sorted, int n) {
    int gw = (blockIdx.x * 256 + threadIdx.x) >> 6;
    int lane = threadIdx.x & 63;
    if (gw >= n) return;
    int s = rs[gw], d = deg[gw];
    float a0 = 0.f, a1 = 0.f;
    int j = 0;
    for (; j + 4 <= d; j += 4) {
        int s0 = sorted[s + j], s1 = sorted[s + j + 1];
        int s2 = sorted[s + j + 2], s3 = sorted[s + j + 3];
        unsigned u0 = a2u[(size_t)s0 * 128 + 64 + lane];
        unsigned u1 = a2u[(size_t)s1 * 128 + 64 + lane];
        unsigned u2 = a2u[(size_t)s2 * 128 + 64 + lane];
        unsigned u3 = a2u[(size_t)s3 * 128 + 64 + lane];
        a0 += bf2f((bf16_t)u0) + bf2f((bf16_t)u1) + bf2f((bf16_t)u2) + bf2f((bf16_t)u3);
        a1 += bf2f((bf16_t)(u0 >> 16)) + bf2f((bf16_t)(u1 >> 16))
            + bf2f((bf16_t)(u2 >> 16)) + bf2f((bf16_t)(u3 >> 16));
    }
    for (; j < d; ++j) {
        unsigned u = a2u[(size_t)sorted[s + j] * 128 + 64 + lane];
        a0 += bf2f((bf16_t)u);
        a1 += bf2f((bf16_t)(u >> 16));
    }
    float dv = dinv[gw];
    a2u[(size_t)gw * 128 + lane] = pack2(a0 * dv, a1 * dv);
}

// ---------------- fused MFMA MLP ----------------
// block = 256 threads = 4 waves; 64 rows per block, 16 rows per wave.
__global__ __launch_bounds__(256) void k_mlp(
    const bf16_t* __restrict__ a2, const bf16_t* __restrict__ Wc1,
    const bf16_t* __restrict__ Wc2, const float* __restrict__ b1,
    bf16_t* __restrict__ g_out /* = a2, cols 0..63 */, float* __restrict__ r_out, int n) {
    __shared__ bf16_t hs[64 * 264];               // h[64][256], stride 264 (bank spread)

    int tid = threadIdx.x;
    int wave = tid >> 6, lane = tid & 63;
    int rA = lane & 15;                           // frag row (A) / out-col (B,D)
    int kA = (lane >> 4) * 8;                     // frag k offset
    int brow = blockIdx.x * 64;
    int wr = brow + wave * 16;

    // ---- phase A: h = relu([m1|x] @ Wc1^T + b1) ----
    f32x4 acc[16];
#pragma unroll
    for (int nt = 0; nt < 16; ++nt) acc[nt] = (f32x4){0.f, 0.f, 0.f, 0.f};

    int arow = wr + rA; if (arow > n - 1) arow = n - 1;   // clamp; rows>=n discarded at store
    const bf16_t* ap = a2 + (size_t)arow * 256 + kA;
#pragma unroll
    for (int k0 = 0; k0 < 8; ++k0) {
        short8 af = *(const short8*)(ap + k0 * 32);
        const bf16_t* bp = Wc1 + (size_t)rA * 256 + k0 * 32 + kA;
#pragma unroll
        for (int nt = 0; nt < 16; ++nt) {
            short8 bf = *(const short8*)(bp + (size_t)nt * 16 * 256);
            acc[nt] = __builtin_amdgcn_mfma_f32_16x16x32_bf16(af, bf, acc[nt], 0, 0, 0);
        }
    }
    int erow = wave * 16 + (lane >> 4) * 4;       // D rows = erow..erow+3 (local)
#pragma unroll
    for (int nt = 0; nt < 16; ++nt) {
        int col = nt * 16 + rA;                   // D col = lane&15
        float bb = b1[col];
#pragma unroll
        for (int r = 0; r < 4; ++r) {
            float v = acc[nt][r] + bb;
            hs[(erow + r) * 264 + col] = f2bf(v > 0.f ? v : 0.f);
        }
    }
    __syncthreads();

    // ---- phase B: [g|r] = h @ Wc2^T ----
    f32x4 acc2[8];
#pragma unroll
    for (int nt = 0; nt < 8; ++nt) acc2[nt] = (f32x4){0.f, 0.f, 0.f, 0.f};

    const bf16_t* hp = hs + (size_t)(wave * 16 + rA) * 264 + kA;
#pragma unroll
    for (int k0 = 0; k0 < 8; ++k0) {
        short8 af = *(const short8*)(hp + k0 * 32);
        const bf16_t* bp = Wc2 + (size_t)rA * 256 + k0 * 32 + kA;
#pragma unroll
        for (int nt = 0; nt < 8; ++nt) {
            short8 bf = *(const short8*)(bp + (size_t)nt * 16 * 256);
            acc2[nt] = __builtin_amdgcn_mfma_f32_16x16x32_bf16(af, bf, acc2[nt], 0, 0, 0);
        }
    }
#pragma unroll
    for (int nt = 0; nt < 8; ++nt) {
        int col = nt * 16 + rA;
#pragma unroll
        for (int r = 0; r < 4; ++r) {
            int row = brow + erow + r;
            if (row < n) {
                float v = acc2[nt][r];
                if (col < 64) g_out[(size_t)row * 256 + col] = f2bf(v);
                else          r_out[(size_t)row * 64 + (col - 64)] = v;
            }
        }
    }
}

// ---------------- aggregation 2 + log_softmax ----------------
__global__ void k_agg2_final(const bf16_t* __restrict__ g /* a2, stride 256 */,
                             const int* __restrict__ rs, const int* __restrict__ deg,
                             const float* __restrict__ dinv, const int* __restrict__ sorted,
                             const float* __restrict__ b2, int n, float* __restrict__ out) {
    int gw = (blockIdx.x * 256 + threadIdx.x) >> 6;
    int lane = threadIdx.x & 63;
    if (gw >= n) return;
    int s = rs[gw], d = deg[gw];
    float a = 0.f;
    int j = 0;
    for (; j + 4 <= d; j += 4) {
        int s0 = sorted[s + j], s1 = sorted[s + j + 1];
        int s2 = sorted[s + j + 2], s3 = sorted[s + j + 3];
        a += bf2f(g[(size_t)s0 * 256 + lane]) + bf2f(g[(size_t)s1 * 256 + lane])
           + bf2f(g[(size_t)s2 * 256 + lane]) + bf2f(g[(size_t)s3 * 256 + lane]);
    }
    for (; j < d; ++j) a += bf2f(g[(size_t)sorted[s + j] * 256 + lane]);

    float o = a * dinv[gw] + out[(size_t)gw * 64 + lane] + b2[lane];
    float m = o;
#pragma unroll
    for (int off = 1; off < 64; off <<= 1) m = fmaxf(m, __shfl_xor(m, off));
    float p = expf(o - m);
    float ssum = p;
#pragma unroll
    for (int off = 1; off < 64; off <<= 1) ssum += __shfl_xor(ssum, off);
    out[(size_t)gw * 64 + lane] = (o - m) - logf(ssum);
}

extern "C" void kernel_launch(void* const* d_in, const int* in_sizes, int n_in,
                              void* d_out, int out_size, void* d_ws, size_t ws_size,
                              hipStream_t stream) {
    const float* x   = (const float*)d_in[0];
    const int*   ei  = (const int*)d_in[1];
    const float* W1l = (const float*)d_in[2];
    const float* W1r = (const float*)d_in[3];
    const float* b1  = (const float*)d_in[4];
    const float* W2l = (const float*)d_in[5];
    const float* W2r = (const float*)d_in[6];
    const float* b2  = (const float*)d_in[7];
    float* out = (float*)d_out;

    const int N = in_sizes[0] / 128;
    const int E = in_sizes[1] / 2;

    // workspace (~59.3 MB), all offsets 16B-aligned
    char* ws = (char*)d_ws;
    size_t off = 0;
    int*    deg  = (int*)(ws + off);    off += (size_t)N * 4;
    int*    rs   = (int*)(ws + off);    off += (size_t)N * 4;
    int*    cur  = (int*)(ws + off);    off += (size_t)N * 4;
    float*  dinv = (float*)(ws + off);  off += (size_t)N * 4;
    int*    bs   = (int*)(ws + off);    off += 16384;
    bf16_t* Wc1  = (bf16_t*)(ws + off); off += 256 * 256 * 2;
    bf16_t* Wc2  = (bf16_t*)(ws + off); off += 128 * 256 * 2;
    int*    sorted = (int*)(ws + off);  off += (size_t)E * 4;
    bf16_t* a2   = (bf16_t*)(ws + off); off += (size_t)N * 256 * 2;  // [m1|x] bf16; g reuses cols 0..63

    (void)hipMemsetAsync(deg, 0, (size_t)N * 4, stream);

    const int nb = (N + 255) / 256;   // 391 <= 1024
    k_hist  <<<(E + 255) / 256, 256, 0, stream>>>(ei, E, N, deg);
    k_scan1 <<<nb, 256, 0, stream>>>(deg, N, rs, bs);
    k_scan2 <<<1, 1024, 0, stream>>>(bs, nb);
    k_scan3 <<<nb, 256, 0, stream>>>(deg, bs, N, rs, cur, dinv);
    k_fill  <<<(E + 255) / 256, 256, 0, stream>>>(ei, E, N, cur, sorted);

    k_cast  <<<(N * 64 + 255) / 256, 256, 0, stream>>>(x, (unsigned*)a2, N);
    k_prepw1<<<256, 256, 0, stream>>>(W1l, W1r, Wc1);
    k_prepw2<<<128, 256, 0, stream>>>(W2l, W2r, Wc2);

    k_agg1  <<<(N * 64 + 255) / 256, 256, 0, stream>>>((unsigned*)a2, rs, deg, dinv, sorted, N);
    k_mlp   <<<(N + 63) / 64, 256, 0, stream>>>(a2, Wc1, Wc2, b1, a2, out, N);
    k_agg2_final<<<(N * 64 + 255) / 256, 256, 0, stream>>>(a2, rs, deg, dinv, sorted, b2, N, out);
}

// Round 7
// 510.339 us; speedup vs baseline: 3.2338x; 1.2200x over previous
//
#include <hip/hip_runtime.h>

// ---------------------------------------------------------------------------
// GraphSAGE 2-layer forward, MFMA v3.
//   CSR build -> prep (x->bf16 into a2 cols 128..255; weights -> MFMA-fragment
//   order Wf1/Wf2) -> agg1 (mean of x, bf16, into a2 cols 0..127)
//   -> k_mlp: stage A-panel (64x256) in LDS frag-order; phase A
//      h=relu(a2@W1+b1) -> h back into same LDS frag-order; phase B
//      g=h@W2l (compact bf16 [N][64]), r=h@W2r (fp32 -> d_out)
//   -> agg2: mean(g[neigh])*dinv + r + b2 -> log_softmax.
// Frag conventions (verified R4/R5 pass): A/B lane l holds M[l&15][(l>>4)*8+j];
// D: col=lane&15, row=(lane>>4)*4+reg.
// Key fix vs R5: B-frags pre-swizzled so the inner-loop weight load is a
// lane-linear contiguous 1KB burst (was 16B x 512B-strided scatter that
// serialized at L2 latency with only 76 VGPRs).
// ---------------------------------------------------------------------------

typedef unsigned short bf16_t;
typedef __attribute__((ext_vector_type(8))) short short8;
typedef __attribute__((ext_vector_type(4))) float f32x4;

static __device__ __forceinline__ bf16_t f2bf(float f) {
    unsigned u = __float_as_uint(f);
    u += 0x7FFFu + ((u >> 16) & 1u);   // round-to-nearest-even
    return (bf16_t)(u >> 16);
}
static __device__ __forceinline__ float bf2f(bf16_t h) {
    return __uint_as_float(((unsigned)h) << 16);
}
static __device__ __forceinline__ unsigned pack2(float lo, float hi) {
    return ((unsigned)f2bf(hi) << 16) | (unsigned)f2bf(lo);
}

// ---------------- CSR build ----------------
__global__ void k_hist(const int* __restrict__ ei, int E, int n, int* __restrict__ deg) {
    int e = blockIdx.x * 256 + threadIdx.x;
    if (e < E) {
        unsigned dst = (unsigned)ei[(size_t)E + e];
        if (dst < (unsigned)n) atomicAdd(&deg[dst], 1);
    }
}

__global__ void k_scan1(const int* __restrict__ deg, int n,
                        int* __restrict__ rs, int* __restrict__ bs) {
    __shared__ int sm[256];
    int i = blockIdx.x * 256 + threadIdx.x;
    int v = (i < n) ? deg[i] : 0;
    sm[threadIdx.x] = v;
    __syncthreads();
    for (int off = 1; off < 256; off <<= 1) {
        int t = (threadIdx.x >= off) ? sm[threadIdx.x - off] : 0;
        __syncthreads();
        sm[threadIdx.x] += t;
        __syncthreads();
    }
    if (i < n) rs[i] = sm[threadIdx.x] - v;
    if (threadIdx.x == 255) bs[blockIdx.x] = sm[255];
}

__global__ void k_scan2(int* bs, int nb) {
    __shared__ int sm[1024];
    int i = threadIdx.x;
    int v = (i < nb) ? bs[i] : 0;
    sm[i] = v;
    __syncthreads();
    for (int off = 1; off < 1024; off <<= 1) {
        int t = (i >= off) ? sm[i - off] : 0;
        __syncthreads();
        sm[i] += t;
        __syncthreads();
    }
    if (i < nb) bs[i] = sm[i] - v;
}

__global__ void k_scan3(const int* __restrict__ deg, const int* __restrict__ bs, int n,
                        int* __restrict__ rs, int* __restrict__ cur, float* __restrict__ dinv) {
    int i = blockIdx.x * 256 + threadIdx.x;
    if (i < n) {
        int v = rs[i] + bs[blockIdx.x];
        rs[i] = v;
        cur[i] = v;
        dinv[i] = 1.0f / fmaxf((float)deg[i], 1.0f);
    }
}

__global__ void k_fill(const int* __restrict__ ei, int E, int n,
                       int* __restrict__ cur, int* __restrict__ sorted) {
    int e = blockIdx.x * 256 + threadIdx.x;
    if (e < E) {
        unsigned src = (unsigned)ei[e];
        unsigned dst = (unsigned)ei[(size_t)E + e];
        if (dst < (unsigned)n && src < (unsigned)n) {
            int pos = atomicAdd(&cur[dst], 1);
            sorted[pos] = (int)src;
        }
    }
}

// ---------------- prep: cast x -> a2 bf16; weights -> fragment order --------
// Wf1[((k0*16+o16)*64+l)*8+j] = W1[k0*32+((l>>4)&3)*8+j][o16*16+(l&15)]  (256 out)
// Wf2[((k0*8 +o16)*64+l)*8+j] = W2[k0*32+((l>>4)&3)*8+j][o16*16+(l&15)]  (128 out)
__global__ void k_prep(const float* __restrict__ x, unsigned* __restrict__ a2u,
                       const float* __restrict__ W1l, const float* __restrict__ W1r,
                       const float* __restrict__ W2l, const float* __restrict__ W2r,
                       bf16_t* __restrict__ Wf1, bf16_t* __restrict__ Wf2, int n) {
    int i = blockIdx.x * 256 + threadIdx.x;
    int nc = n * 64;
    if (i < nc) {
        int row = i >> 6, c2 = i & 63;
        float2 v = *(const float2*)&x[(size_t)row * 128 + c2 * 2];
        a2u[(size_t)row * 128 + 64 + c2] = pack2(v.x, v.y);
    } else if (i < nc + 65536) {
        int t = i - nc;
        int j = t & 7, l = (t >> 3) & 63, o16 = (t >> 9) & 15, k0 = t >> 13;
        int o = o16 * 16 + (l & 15);
        int k = k0 * 32 + ((l >> 4) & 3) * 8 + j;
        float v = (k < 128) ? W1l[(size_t)k * 256 + o] : W1r[(size_t)(k - 128) * 256 + o];
        Wf1[t] = f2bf(v);
    } else if (i < nc + 65536 + 32768) {
        int t = i - nc - 65536;
        int j = t & 7, l = (t >> 3) & 63, o16 = (t >> 9) & 7, k0 = t >> 12;
        int o = o16 * 16 + (l & 15);
        int k = k0 * 32 + ((l >> 4) & 3) * 8 + j;
        float v = (o < 64) ? W2l[(size_t)k * 64 + o] : W2r[(size_t)k * 64 + (o - 64)];
        Wf2[t] = f2bf(v);
    }
}

// ---------------- aggregation 1 ----------------
__global__ void k_agg1(unsigned* __restrict__ a2u, const int* __restrict__ rs,
                       const int* __restrict__ deg, const float* __restrict__ dinv,
                       const int* __restrict__ sorted, int n) {
    int gw = (blockIdx.x * 256 + threadIdx.x) >> 6;
    int lane = threadIdx.x & 63;
    if (gw >= n) return;
    int s = rs[gw], d = deg[gw];
    float a0 = 0.f, a1 = 0.f;
    int j = 0;
    for (; j + 8 <= d; j += 8) {   // 8 independent gathers in flight
        int ss[8];
#pragma unroll
        for (int q = 0; q < 8; ++q) ss[q] = sorted[s + j + q];
        unsigned uu[8];
#pragma unroll
        for (int q = 0; q < 8; ++q) uu[q] = a2u[(size_t)ss[q] * 128 + 64 + lane];
#pragma unroll
        for (int q = 0; q < 8; ++q) {
            a0 += bf2f((bf16_t)uu[q]);
            a1 += bf2f((bf16_t)(uu[q] >> 16));
        }
    }
    for (; j < d; ++j) {
        unsigned u = a2u[(size_t)sorted[s + j] * 128 + 64 + lane];
        a0 += bf2f((bf16_t)u);
        a1 += bf2f((bf16_t)(u >> 16));
    }
    float dv = dinv[gw];
    a2u[(size_t)gw * 128 + lane] = pack2(a0 * dv, a1 * dv);
}

// ---------------- fused MFMA MLP ----------------
// 256 threads = 4 waves; 64 rows/block. LDS = one 32KB frag-order panel,
// used first for A (input), then (after barrier) for h.
__global__ __launch_bounds__(256) void k_mlp(
    const bf16_t* __restrict__ a2, const bf16_t* __restrict__ Wf1,
    const bf16_t* __restrict__ Wf2, const float* __restrict__ b1,
    bf16_t* __restrict__ g, float* __restrict__ r_out, int n) {
    __shared__ bf16_t sh[16384];   // 32KB, chunk c (16B) = (k0*4+rt)*64+lane

    int tid = threadIdx.x;
    int wave = tid >> 6, lane = tid & 63;
    int brow = blockIdx.x * 64;
    int c15 = lane & 15, rl4 = (lane >> 4) * 4;

    // stage A panel (64 rows x 256 k) into frag order; dest is thread-linear.
    {
        int r = brow + ((tid >> 6) << 4) + (tid & 15);
        if (r > n - 1) r = n - 1;                      // clamp; tail rows discarded at store
        const bf16_t* src = a2 + (size_t)r * 256 + ((tid >> 4) & 3) * 8;
        short8* dst = (short8*)sh;
#pragma unroll
        for (int i = 0; i < 8; ++i)
            dst[i * 256 + tid] = *(const short8*)(src + i * 32);
    }

    // preload bias for this wave's 64 output cols
    float bb[4];
#pragma unroll
    for (int nt = 0; nt < 4; ++nt) bb[nt] = b1[wave * 64 + nt * 16 + c15];

    __syncthreads();

    // ---- phase A: h[64][256] = relu(A @ W1 + b1) ----
    f32x4 acc[4][4];               // [rt][nt]
#pragma unroll
    for (int rt = 0; rt < 4; ++rt)
#pragma unroll
        for (int nt = 0; nt < 4; ++nt) acc[rt][nt] = (f32x4){0.f, 0.f, 0.f, 0.f};

#pragma unroll
    for (int k0 = 0; k0 < 8; ++k0) {
        short8 af[4];
#pragma unroll
        for (int rt = 0; rt < 4; ++rt)
            af[rt] = ((const short8*)sh)[(k0 * 4 + rt) * 64 + lane];
#pragma unroll
        for (int nt = 0; nt < 4; ++nt) {
            short8 bf = *(const short8*)(Wf1 + ((size_t)((k0 * 16 + wave * 4 + nt) * 64 + lane)) * 8);
#pragma unroll
            for (int rt = 0; rt < 4; ++rt)
                acc[rt][nt] = __builtin_amdgcn_mfma_f32_16x16x32_bf16(af[rt], bf, acc[rt][nt], 0, 0, 0);
        }
    }
    __syncthreads();               // everyone done reading A panel

    // write h into the same LDS, frag order for phase B
#pragma unroll
    for (int nt = 0; nt < 4; ++nt) {
        int kcol = wave * 64 + nt * 16 + c15;          // h column = phase-B k index
        int k0h = kcol >> 5, kslot = (kcol >> 3) & 3, jh = kcol & 7;
#pragma unroll
        for (int rt = 0; rt < 4; ++rt)
#pragma unroll
            for (int r = 0; r < 4; ++r) {
                float v = acc[rt][nt][r] + bb[nt];
                int lane_p = (rl4 + r) | (kslot << 4);
                sh[((k0h * 4 + rt) * 64 + lane_p) * 8 + jh] = f2bf(v > 0.f ? v : 0.f);
            }
    }
    __syncthreads();

    // ---- phase B: [g|r][64][128] = h @ W2 ----
    f32x4 acc2[4][2];
#pragma unroll
    for (int rt = 0; rt < 4; ++rt)
#pragma unroll
        for (int nt = 0; nt < 2; ++nt) acc2[rt][nt] = (f32x4){0.f, 0.f, 0.f, 0.f};

#pragma unroll
    for (int k0 = 0; k0 < 8; ++k0) {
        short8 af[4];
#pragma unroll
        for (int rt = 0; rt < 4; ++rt)
            af[rt] = ((const short8*)sh)[(k0 * 4 + rt) * 64 + lane];
#pragma unroll
        for (int nt = 0; nt < 2; ++nt) {
            short8 bf = *(const short8*)(Wf2 + ((size_t)((k0 * 8 + wave * 2 + nt) * 64 + lane)) * 8);
#pragma unroll
            for (int rt = 0; rt < 4; ++rt)
                acc2[rt][nt] = __builtin_amdgcn_mfma_f32_16x16x32_bf16(af[rt], bf, acc2[rt][nt], 0, 0, 0);
        }
    }

#pragma unroll
    for (int nt = 0; nt < 2; ++nt) {
        int col = wave * 32 + nt * 16 + c15;           // wave-uniform g-vs-r split
#pragma unroll
        for (int rt = 0; rt < 4; ++rt)
#pragma unroll
            for (int r = 0; r < 4; ++r) {
                int row = brow + rt * 16 + rl4 + r;
                if (row < n) {
                    float v = acc2[rt][nt][r];
                    if (col < 64) g[(size_t)row * 64 + col] = f2bf(v);
                    else          r_out[(size_t)row * 64 + (col - 64)] = v;
                }
            }
    }
}

// ---------------- aggregation 2 + log_softmax ----------------
__global__ void k_agg2_final(const bf16_t* __restrict__ g, const int* __restrict__ rs,
                             const int* __restrict__ deg, const float* __restrict__ dinv,
                             const int* __restrict__ sorted, const float* __restrict__ b2,
                             int n, float* __restrict__ out) {
    int gw = (blockIdx.x * 256 + threadIdx.x) >> 6;
    int lane = threadIdx.x & 63;
    if (gw >= n) return;
    int s = rs[gw], d = deg[gw];
    float a = 0.f;
    int j = 0;
    for (; j + 8 <= d; j += 8) {
        int ss[8];
#pragma unroll
        for (int q = 0; q < 8; ++q) ss[q] = sorted[s + j + q];
        bf16_t vv[8];
#pragma unroll
        for (int q = 0; q < 8; ++q) vv[q] = g[(size_t)ss[q] * 64 + lane];
#pragma unroll
        for (int q = 0; q < 8; ++q) a += bf2f(vv[q]);
    }
    for (; j < d; ++j) a += bf2f(g[(size_t)sorted[s + j] * 64 + lane]);

    float o = a * dinv[gw] + out[(size_t)gw * 64 + lane] + b2[lane];
    float m = o;
#pragma unroll
    for (int off = 1; off < 64; off <<= 1) m = fmaxf(m, __shfl_xor(m, off));
    float p = expf(o - m);
    float ssum = p;
#pragma unroll
    for (int off = 1; off < 64; off <<= 1) ssum += __shfl_xor(ssum, off);
    out[(size_t)gw * 64 + lane] = (o - m) - logf(ssum);
}

extern "C" void kernel_launch(void* const* d_in, const int* in_sizes, int n_in,
                              void* d_out, int out_size, void* d_ws, size_t ws_size,
                              hipStream_t stream) {
    const float* x   = (const float*)d_in[0];
    const int*   ei  = (const int*)d_in[1];
    const float* W1l = (const float*)d_in[2];
    const float* W1r = (const float*)d_in[3];
    const float* b1  = (const float*)d_in[4];
    const float* W2l = (const float*)d_in[5];
    const float* W2r = (const float*)d_in[6];
    const float* b2  = (const float*)d_in[7];
    float* out = (float*)d_out;

    const int N = in_sizes[0] / 128;
    const int E = in_sizes[1] / 2;

    // workspace (~72 MB), all offsets 16B-aligned
    char* ws = (char*)d_ws;
    size_t off = 0;
    int*    deg  = (int*)(ws + off);    off += (size_t)N * 4;
    int*    rs   = (int*)(ws + off);    off += (size_t)N * 4;
    int*    cur  = (int*)(ws + off);    off += (size_t)N * 4;
    float*  dinv = (float*)(ws + off);  off += (size_t)N * 4;
    int*    bs   = (int*)(ws + off);    off += 16384;
    bf16_t* Wf1  = (bf16_t*)(ws + off); off += 65536 * 2;
    bf16_t* Wf2  = (bf16_t*)(ws + off); off += 32768 * 2;
    int*    sorted = (int*)(ws + off);  off += (size_t)E * 4;
    bf16_t* a2   = (bf16_t*)(ws + off); off += (size_t)N * 256 * 2;  // [m1|x] bf16
    bf16_t* g    = (bf16_t*)(ws + off); off += (size_t)N * 64 * 2;   // compact layer2-left

    (void)hipMemsetAsync(deg, 0, (size_t)N * 4, stream);

    const int nb = (N + 255) / 256;   // 391 <= 1024
    k_hist  <<<(E + 255) / 256, 256, 0, stream>>>(ei, E, N, deg);
    k_scan1 <<<nb, 256, 0, stream>>>(deg, N, rs, bs);
    k_scan2 <<<1, 1024, 0, stream>>>(bs, nb);
    k_scan3 <<<nb, 256, 0, stream>>>(deg, bs, N, rs, cur, dinv);
    k_fill  <<<(E + 255) / 256, 256, 0, stream>>>(ei, E, N, cur, sorted);

    k_prep  <<<(N * 64 + 98304 + 255) / 256, 256, 0, stream>>>(x, (unsigned*)a2,
                                                               W1l, W1r, W2l, W2r, Wf1, Wf2, N);
    k_agg1  <<<(N * 64 + 255) / 256, 256, 0, stream>>>((unsigned*)a2, rs, deg, dinv, sorted, N);
    k_mlp   <<<(N + 63) / 64, 256, 0, stream>>>(a2, Wf1, Wf2, b1, g, out, N);
    k_agg2_final<<<(N * 64 + 255) / 256, 256, 0, stream>>>(g, rs, deg, dinv, sorted, b2, N, out);
}

// Round 8
// 354.786 us; speedup vs baseline: 4.6516x; 1.4384x over previous
//
#include <hip/hip_runtime.h>

// ---------------------------------------------------------------------------
// GraphSAGE 2-layer forward, MFMA v4.
//   CSR via bucketed counting sort (no global atomics, ~1x write amplification):
//     kb_hist    : per-block LDS hist of bucket = dst>>8          -> C[blk][bk]
//     kb_scanA   : exclusive scan over blocks per bucket (inplace) -> totals T
//     kb_scanB   : exclusive scan over buckets                     -> bases B
//     kb_scatter : edges -> bucket regions, packed (dl<<24|src), runs are
//                  sequential per (block,bucket) => full-line writes
//     kb_finalize: per bucket (256 nodes): LDS stage + per-node hist/scan ->
//                  deg/rs/dinv coalesced; node-exact scatter in LDS; sorted
//                  written back linearly IN PLACE over the bucketed array.
//   Then: prep (x->bf16 into a2; weights -> MFMA frag order) -> agg1 ->
//   k_mlp (MFMA, h in LDS) -> agg2 + log_softmax.
// Layer-2 agg after projection: segment_sum(h[src])@W2l == segment_sum((h@W2l)[src]).
// Frag conventions (verified R5/R7 pass): A/B lane l holds M[l&15][(l>>4)*8+j];
// D: col=lane&15, row=(lane>>4)*4+reg.
// ---------------------------------------------------------------------------

typedef unsigned short bf16_t;
typedef __attribute__((ext_vector_type(8))) short short8;
typedef __attribute__((ext_vector_type(4))) float f32x4;

static __device__ __forceinline__ bf16_t f2bf(float f) {
    unsigned u = __float_as_uint(f);
    u += 0x7FFFu + ((u >> 16) & 1u);   // round-to-nearest-even
    return (bf16_t)(u >> 16);
}
static __device__ __forceinline__ float bf2f(bf16_t h) {
    return __uint_as_float(((unsigned)h) << 16);
}
static __device__ __forceinline__ unsigned pack2(float lo, float hi) {
    return ((unsigned)f2bf(hi) << 16) | (unsigned)f2bf(lo);
}

#define NBLK 256      // blocks for hist/scatter (must be 256: scanA uses 256 thr)
#define BCAP 8192     // max edges per bucket staged in LDS (actual max ~4400)

// ---------------- bucketed counting sort ----------------
__global__ void kb_hist(const int* __restrict__ ei, int E, int chunk, int n, int nbk,
                        int* __restrict__ C) {
    __shared__ int h[512];
    for (int i = threadIdx.x; i < nbk; i += 256) h[i] = 0;
    __syncthreads();
    int start = blockIdx.x * chunk;
    int end = min(E, start + chunk);
    for (int e = start + (int)threadIdx.x; e < end; e += 256) {
        unsigned dst = (unsigned)ei[(size_t)E + e];
        if (dst < (unsigned)n) atomicAdd(&h[dst >> 8], 1);
    }
    __syncthreads();
    for (int i = threadIdx.x; i < nbk; i += 256)
        C[blockIdx.x * nbk + i] = h[i];
}

// one block per bucket: exclusive scan of C[blk][bk] over blk (in place), total -> T
__global__ void kb_scanA(int* __restrict__ C, int nbk, int* __restrict__ T) {
    __shared__ int sm[256];
    int bk = blockIdx.x;
    int v = C[threadIdx.x * nbk + bk];
    sm[threadIdx.x] = v;
    __syncthreads();
    for (int off = 1; off < 256; off <<= 1) {
        int t = (threadIdx.x >= off) ? sm[threadIdx.x - off] : 0;
        __syncthreads();
        sm[threadIdx.x] += t;
        __syncthreads();
    }
    C[threadIdx.x * nbk + bk] = sm[threadIdx.x] - v;   // exclusive over blocks
    if (threadIdx.x == 255) T[bk] = sm[255];
}

// single block: exclusive scan of bucket totals -> B[0..nbk], B[nbk]=E_valid
__global__ void kb_scanB(const int* __restrict__ T, int nbk, int* __restrict__ B) {
    __shared__ int sm[512];
    int i = threadIdx.x;
    int v = (i < nbk) ? T[i] : 0;
    sm[i] = v;
    __syncthreads();
    for (int off = 1; off < 512; off <<= 1) {
        int t = (i >= off) ? sm[i - off] : 0;
        __syncthreads();
        sm[i] += t;
        __syncthreads();
    }
    if (i < nbk) B[i] = sm[i] - v;
    if (i == nbk - 1) B[nbk] = sm[i];
}

__global__ void kb_scatter(const int* __restrict__ ei, int E, int chunk, int n, int nbk,
                           const int* __restrict__ C, const int* __restrict__ B,
                           unsigned* __restrict__ bucketed) {
    __shared__ int curb[512];
    for (int i = threadIdx.x; i < nbk; i += 256)
        curb[i] = B[i] + C[blockIdx.x * nbk + i];
    __syncthreads();
    int start = blockIdx.x * chunk;
    int end = min(E, start + chunk);
    for (int e = start + (int)threadIdx.x; e < end; e += 256) {
        unsigned src = (unsigned)ei[e];
        unsigned dst = (unsigned)ei[(size_t)E + e];
        if (dst < (unsigned)n) {
            if (src >= (unsigned)n) src = 0u;          // clamp: keep counts consistent
            int pos = atomicAdd(&curb[dst >> 8], 1);   // LDS atomic
            bucketed[pos] = ((dst & 255u) << 24) | src;
        }
    }
}

// one block per bucket; sorted aliases bucketed (in-place via LDS staging).
__global__ __launch_bounds__(256) void kb_finalize(
    unsigned* __restrict__ bucketed, const int* __restrict__ B, int n,
    int* __restrict__ deg, int* __restrict__ rs_, float* __restrict__ dinv) {
    __shared__ unsigned ebuf[BCAP];
    __shared__ unsigned sbuf[BCAP];
    __shared__ int h[256], sc[256], cur2[256];
    int bk = blockIdx.x;
    int base = B[bk];
    int cnt = B[bk + 1] - base;
    if (cnt > BCAP) cnt = BCAP;                        // impossible for this input
    for (int i = threadIdx.x; i < cnt; i += 256) ebuf[i] = bucketed[base + i];
    h[threadIdx.x] = 0;
    __syncthreads();
    for (int i = threadIdx.x; i < cnt; i += 256) atomicAdd(&h[ebuf[i] >> 24], 1);
    __syncthreads();
    int v = h[threadIdx.x];
    sc[threadIdx.x] = v;
    __syncthreads();
    for (int off = 1; off < 256; off <<= 1) {
        int t = (threadIdx.x >= off) ? sc[threadIdx.x - off] : 0;
        __syncthreads();
        sc[threadIdx.x] += t;
        __syncthreads();
    }
    int excl = sc[threadIdx.x] - v;
    int node = bk * 256 + (int)threadIdx.x;
    if (node < n) {
        deg[node] = v;
        rs_[node] = base + excl;
        dinv[node] = 1.0f / fmaxf((float)v, 1.0f);
    }
    cur2[threadIdx.x] = excl;
    __syncthreads();
    for (int i = threadIdx.x; i < cnt; i += 256) {
        unsigned u = ebuf[i];
        int p = atomicAdd(&cur2[u >> 24], 1);
        sbuf[p] = u & 0xFFFFFFu;
    }
    __syncthreads();
    for (int i = threadIdx.x; i < cnt; i += 256) bucketed[base + i] = sbuf[i];
}

// ---------------- prep: cast x -> a2 bf16; weights -> fragment order --------
// Wf1[((k0*16+o16)*64+l)*8+j] = W1[k0*32+((l>>4)&3)*8+j][o16*16+(l&15)]  (256 out)
// Wf2[((k0*8 +o16)*64+l)*8+j] = W2[k0*32+((l>>4)&3)*8+j][o16*16+(l&15)]  (128 out)
__global__ void k_prep(const float* __restrict__ x, unsigned* __restrict__ a2u,
                       const float* __restrict__ W1l, const float* __restrict__ W1r,
                       const float* __restrict__ W2l, const float* __restrict__ W2r,
                       bf16_t* __restrict__ Wf1, bf16_t* __restrict__ Wf2, int n) {
    int i = blockIdx.x * 256 + threadIdx.x;
    int nc = n * 64;
    if (i < nc) {
        int row = i >> 6, c2 = i & 63;
        float2 v = *(const float2*)&x[(size_t)row * 128 + c2 * 2];
        a2u[(size_t)row * 128 + 64 + c2] = pack2(v.x, v.y);
    } else if (i < nc + 65536) {
        int t = i - nc;
        int j = t & 7, l = (t >> 3) & 63, o16 = (t >> 9) & 15, k0 = t >> 13;
        int o = o16 * 16 + (l & 15);
        int k = k0 * 32 + ((l >> 4) & 3) * 8 + j;
        float v = (k < 128) ? W1l[(size_t)k * 256 + o] : W1r[(size_t)(k - 128) * 256 + o];
        Wf1[t] = f2bf(v);
    } else if (i < nc + 65536 + 32768) {
        int t = i - nc - 65536;
        int j = t & 7, l = (t >> 3) & 63, o16 = (t >> 9) & 7, k0 = t >> 12;
        int o = o16 * 16 + (l & 15);
        int k = k0 * 32 + ((l >> 4) & 3) * 8 + j;
        float v = (o < 64) ? W2l[(size_t)k * 64 + o] : W2r[(size_t)k * 64 + (o - 64)];
        Wf2[t] = f2bf(v);
    }
}

// ---------------- aggregation 1 ----------------
__global__ void k_agg1(unsigned* __restrict__ a2u, const int* __restrict__ rs,
                       const int* __restrict__ deg, const float* __restrict__ dinv,
                       const int* __restrict__ sorted, int n) {
    int gw = (blockIdx.x * 256 + threadIdx.x) >> 6;
    int lane = threadIdx.x & 63;
    if (gw >= n) return;
    int s = rs[gw], d = deg[gw];
    float a0 = 0.f, a1 = 0.f;
    int j = 0;
    for (; j + 8 <= d; j += 8) {   // 8 independent gathers in flight
        int ss[8];
#pragma unroll
        for (int q = 0; q < 8; ++q) ss[q] = sorted[s + j + q];
        unsigned uu[8];
#pragma unroll
        for (int q = 0; q < 8; ++q) uu[q] = a2u[(size_t)ss[q] * 128 + 64 + lane];
#pragma unroll
        for (int q = 0; q < 8; ++q) {
            a0 += bf2f((bf16_t)uu[q]);
            a1 += bf2f((bf16_t)(uu[q] >> 16));
        }
    }
    for (; j < d; ++j) {
        unsigned u = a2u[(size_t)sorted[s + j] * 128 + 64 + lane];
        a0 += bf2f((bf16_t)u);
        a1 += bf2f((bf16_t)(u >> 16));
    }
    float dv = dinv[gw];
    a2u[(size_t)gw * 128 + lane] = pack2(a0 * dv, a1 * dv);
}

// ---------------- fused MFMA MLP ----------------
__global__ __launch_bounds__(256) void k_mlp(
    const bf16_t* __restrict__ a2, const bf16_t* __restrict__ Wf1,
    const bf16_t* __restrict__ Wf2, const float* __restrict__ b1,
    bf16_t* __restrict__ g, float* __restrict__ r_out, int n) {
    __shared__ bf16_t sh[16384];   // 32KB, chunk c (16B) = (k0*4+rt)*64+lane

    int tid = threadIdx.x;
    int wave = tid >> 6, lane = tid & 63;
    int brow = blockIdx.x * 64;
    int c15 = lane & 15, rl4 = (lane >> 4) * 4;

    // stage A panel (64 rows x 256 k) into frag order; dest is thread-linear.
    {
        int r = brow + ((tid >> 6) << 4) + (tid & 15);
        if (r > n - 1) r = n - 1;                      // clamp; tail rows discarded at store
        const bf16_t* src = a2 + (size_t)r * 256 + ((tid >> 4) & 3) * 8;
        short8* dst = (short8*)sh;
#pragma unroll
        for (int i = 0; i < 8; ++i)
            dst[i * 256 + tid] = *(const short8*)(src + i * 32);
    }

    float bb[4];
#pragma unroll
    for (int nt = 0; nt < 4; ++nt) bb[nt] = b1[wave * 64 + nt * 16 + c15];

    __syncthreads();

    // ---- phase A: h[64][256] = relu(A @ W1 + b1) ----
    f32x4 acc[4][4];
#pragma unroll
    for (int rt = 0; rt < 4; ++rt)
#pragma unroll
        for (int nt = 0; nt < 4; ++nt) acc[rt][nt] = (f32x4){0.f, 0.f, 0.f, 0.f};

#pragma unroll
    for (int k0 = 0; k0 < 8; ++k0) {
        short8 af[4];
#pragma unroll
        for (int rt = 0; rt < 4; ++rt)
            af[rt] = ((const short8*)sh)[(k0 * 4 + rt) * 64 + lane];
#pragma unroll
        for (int nt = 0; nt < 4; ++nt) {
            short8 bf = *(const short8*)(Wf1 + ((size_t)((k0 * 16 + wave * 4 + nt) * 64 + lane)) * 8);
#pragma unroll
            for (int rt = 0; rt < 4; ++rt)
                acc[rt][nt] = __builtin_amdgcn_mfma_f32_16x16x32_bf16(af[rt], bf, acc[rt][nt], 0, 0, 0);
        }
    }
    __syncthreads();

    // write h into the same LDS, frag order for phase B
#pragma unroll
    for (int nt = 0; nt < 4; ++nt) {
        int kcol = wave * 64 + nt * 16 + c15;
        int k0h = kcol >> 5, kslot = (kcol >> 3) & 3, jh = kcol & 7;
#pragma unroll
        for (int rt = 0; rt < 4; ++rt)
#pragma unroll
            for (int r = 0; r < 4; ++r) {
                float v = acc[rt][nt][r] + bb[nt];
                int lane_p = (rl4 + r) | (kslot << 4);
                sh[((k0h * 4 + rt) * 64 + lane_p) * 8 + jh] = f2bf(v > 0.f ? v : 0.f);
            }
    }
    __syncthreads();

    // ---- phase B: [g|r][64][128] = h @ W2 ----
    f32x4 acc2[4][2];
#pragma unroll
    for (int rt = 0; rt < 4; ++rt)
#pragma unroll
        for (int nt = 0; nt < 2; ++nt) acc2[rt][nt] = (f32x4){0.f, 0.f, 0.f, 0.f};

#pragma unroll
    for (int k0 = 0; k0 < 8; ++k0) {
        short8 af[4];
#pragma unroll
        for (int rt = 0; rt < 4; ++rt)
            af[rt] = ((const short8*)sh)[(k0 * 4 + rt) * 64 + lane];
#pragma unroll
        for (int nt = 0; nt < 2; ++nt) {
            short8 bf = *(const short8*)(Wf2 + ((size_t)((k0 * 8 + wave * 2 + nt) * 64 + lane)) * 8);
#pragma unroll
            for (int rt = 0; rt < 4; ++rt)
                acc2[rt][nt] = __builtin_amdgcn_mfma_f32_16x16x32_bf16(af[rt], bf, acc2[rt][nt], 0, 0, 0);
        }
    }

#pragma unroll
    for (int nt = 0; nt < 2; ++nt) {
        int col = wave * 32 + nt * 16 + c15;
#pragma unroll
        for (int rt = 0; rt < 4; ++rt)
#pragma unroll
            for (int r = 0; r < 4; ++r) {
                int row = brow + rt * 16 + rl4 + r;
                if (row < n) {
                    float v = acc2[rt][nt][r];
                    if (col < 64) g[(size_t)row * 64 + col] = f2bf(v);
                    else          r_out[(size_t)row * 64 + (col - 64)] = v;
                }
            }
    }
}

// ---------------- aggregation 2 + log_softmax ----------------
__global__ void k_agg2_final(const bf16_t* __restrict__ g, const int* __restrict__ rs,
                             const int* __restrict__ deg, const float* __restrict__ dinv,
                             const int* __restrict__ sorted, const float* __restrict__ b2,
                             int n, float* __restrict__ out) {
    int gw = (blockIdx.x * 256 + threadIdx.x) >> 6;
    int lane = threadIdx.x & 63;
    if (gw >= n) return;
    int s = rs[gw], d = deg[gw];
    float a = 0.f;
    int j = 0;
    for (; j + 8 <= d; j += 8) {
        int ss[8];
#pragma unroll
        for (int q = 0; q < 8; ++q) ss[q] = sorted[s + j + q];
        bf16_t vv[8];
#pragma unroll
        for (int q = 0; q < 8; ++q) vv[q] = g[(size_t)ss[q] * 64 + lane];
#pragma unroll
        for (int q = 0; q < 8; ++q) a += bf2f(vv[q]);
    }
    for (; j < d; ++j) a += bf2f(g[(size_t)sorted[s + j] * 64 + lane]);

    float o = a * dinv[gw] + out[(size_t)gw * 64 + lane] + b2[lane];
    float m = o;
#pragma unroll
    for (int off = 1; off < 64; off <<= 1) m = fmaxf(m, __shfl_xor(m, off));
    float p = expf(o - m);
    float ssum = p;
#pragma unroll
    for (int off = 1; off < 64; off <<= 1) ssum += __shfl_xor(ssum, off);
    out[(size_t)gw * 64 + lane] = (o - m) - logf(ssum);
}

extern "C" void kernel_launch(void* const* d_in, const int* in_sizes, int n_in,
                              void* d_out, int out_size, void* d_ws, size_t ws_size,
                              hipStream_t stream) {
    const float* x   = (const float*)d_in[0];
    const int*   ei  = (const int*)d_in[1];
    const float* W1l = (const float*)d_in[2];
    const float* W1r = (const float*)d_in[3];
    const float* b1  = (const float*)d_in[4];
    const float* W2l = (const float*)d_in[5];
    const float* W2r = (const float*)d_in[6];
    const float* b2  = (const float*)d_in[7];
    float* out = (float*)d_out;

    const int N = in_sizes[0] / 128;
    const int E = in_sizes[1] / 2;
    const int nbk = (N + 255) >> 8;          // 391 buckets of 256 nodes (<=512)
    const int chunk = (E + NBLK - 1) / NBLK; // edges per hist/scatter block

    // workspace (~72 MB), all offsets 16B-aligned
    char* ws = (char*)d_ws;
    size_t off = 0;
    int*    deg  = (int*)(ws + off);    off += (size_t)N * 4;
    int*    rs   = (int*)(ws + off);    off += (size_t)N * 4;
    float*  dinv = (float*)(ws + off);  off += (size_t)N * 4;
    int*    C    = (int*)(ws + off);    off += (size_t)NBLK * nbk * 4;   // [blk][bk]
    int*    T    = (int*)(ws + off);    off += 2048;
    int*    B    = (int*)(ws + off);    off += 2048;
    bf16_t* Wf1  = (bf16_t*)(ws + off); off += 65536 * 2;
    bf16_t* Wf2  = (bf16_t*)(ws + off); off += 32768 * 2;
    int*    sorted = (int*)(ws + off);  off += (size_t)E * 4;            // also bucketed
    bf16_t* a2   = (bf16_t*)(ws + off); off += (size_t)N * 256 * 2;
    bf16_t* g    = (bf16_t*)(ws + off); off += (size_t)N * 64 * 2;

    kb_hist    <<<NBLK, 256, 0, stream>>>(ei, E, chunk, N, nbk, C);
    kb_scanA   <<<nbk, 256, 0, stream>>>(C, nbk, T);
    kb_scanB   <<<1, 512, 0, stream>>>(T, nbk, B);
    kb_scatter <<<NBLK, 256, 0, stream>>>(ei, E, chunk, N, nbk, C, B, (unsigned*)sorted);
    kb_finalize<<<nbk, 256, 0, stream>>>((unsigned*)sorted, B, N, deg, rs, dinv);

    k_prep  <<<(N * 64 + 98304 + 255) / 256, 256, 0, stream>>>(x, (unsigned*)a2,
                                                               W1l, W1r, W2l, W2r, Wf1, Wf2, N);
    k_agg1  <<<(N * 64 + 255) / 256, 256, 0, stream>>>((unsigned*)a2, rs, deg, dinv, sorted, N);
    k_mlp   <<<(N + 63) / 64, 256, 0, stream>>>(a2, Wf1, Wf2, b1, g, out, N);
    k_agg2_final<<<(N * 64 + 255) / 256, 256, 0, stream>>>(g, rs, deg, dinv, sorted, b2, N, out);
}

// Round 9
// 334.980 us; speedup vs baseline: 4.9266x; 1.0591x over previous
//
#include <hip/hip_runtime.h>

// ---------------------------------------------------------------------------
// GraphSAGE 2-layer forward, MFMA v5.
//   CSR via bucketed counting sort (R8) -> prep (x->bf16 a2; weights -> MFMA
//   frag order) -> agg1 (half-wave uint2 gather) -> k_mlp (MFMA, h in LDS,
//   r out as bf16) -> agg2 (quarter-wave uint2 gather) + log_softmax.
// Gather loops use wide loads + wave-splitting: more bytes/instruction and
// more loads in flight (R8 agg2 was ushort-gather latency-bound at 21% HBM).
// ---------------------------------------------------------------------------

typedef unsigned short bf16_t;
typedef __attribute__((ext_vector_type(8))) short short8;
typedef __attribute__((ext_vector_type(4))) float f32x4;

static __device__ __forceinline__ bf16_t f2bf(float f) {
    unsigned u = __float_as_uint(f);
    u += 0x7FFFu + ((u >> 16) & 1u);   // round-to-nearest-even
    return (bf16_t)(u >> 16);
}
static __device__ __forceinline__ float bf2f(bf16_t h) {
    return __uint_as_float(((unsigned)h) << 16);
}
static __device__ __forceinline__ unsigned pack2(float lo, float hi) {
    return ((unsigned)f2bf(hi) << 16) | (unsigned)f2bf(lo);
}

#define NBLK 256
#define BCAP 8192

// ---------------- bucketed counting sort ----------------
__global__ void kb_hist(const int* __restrict__ ei, int E, int chunk, int n, int nbk,
                        int* __restrict__ C) {
    __shared__ int h[512];
    for (int i = threadIdx.x; i < nbk; i += 256) h[i] = 0;
    __syncthreads();
    int start = blockIdx.x * chunk;
    int end = min(E, start + chunk);
    for (int e = start + (int)threadIdx.x; e < end; e += 256) {
        unsigned dst = (unsigned)ei[(size_t)E + e];
        if (dst < (unsigned)n) atomicAdd(&h[dst >> 8], 1);
    }
    __syncthreads();
    for (int i = threadIdx.x; i < nbk; i += 256)
        C[blockIdx.x * nbk + i] = h[i];
}

__global__ void kb_scanA(int* __restrict__ C, int nbk, int* __restrict__ T) {
    __shared__ int sm[256];
    int bk = blockIdx.x;
    int v = C[threadIdx.x * nbk + bk];
    sm[threadIdx.x] = v;
    __syncthreads();
    for (int off = 1; off < 256; off <<= 1) {
        int t = (threadIdx.x >= off) ? sm[threadIdx.x - off] : 0;
        __syncthreads();
        sm[threadIdx.x] += t;
        __syncthreads();
    }
    C[threadIdx.x * nbk + bk] = sm[threadIdx.x] - v;
    if (threadIdx.x == 255) T[bk] = sm[255];
}

__global__ void kb_scanB(const int* __restrict__ T, int nbk, int* __restrict__ B) {
    __shared__ int sm[512];
    int i = threadIdx.x;
    int v = (i < nbk) ? T[i] : 0;
    sm[i] = v;
    __syncthreads();
    for (int off = 1; off < 512; off <<= 1) {
        int t = (i >= off) ? sm[i - off] : 0;
        __syncthreads();
        sm[i] += t;
        __syncthreads();
    }
    if (i < nbk) B[i] = sm[i] - v;
    if (i == nbk - 1) B[nbk] = sm[i];
}

__global__ void kb_scatter(const int* __restrict__ ei, int E, int chunk, int n, int nbk,
                           const int* __restrict__ C, const int* __restrict__ B,
                           unsigned* __restrict__ bucketed) {
    __shared__ int curb[512];
    for (int i = threadIdx.x; i < nbk; i += 256)
        curb[i] = B[i] + C[blockIdx.x * nbk + i];
    __syncthreads();
    int start = blockIdx.x * chunk;
    int end = min(E, start + chunk);
    for (int e = start + (int)threadIdx.x; e < end; e += 256) {
        unsigned src = (unsigned)ei[e];
        unsigned dst = (unsigned)ei[(size_t)E + e];
        if (dst < (unsigned)n) {
            if (src >= (unsigned)n) src = 0u;
            int pos = atomicAdd(&curb[dst >> 8], 1);
            bucketed[pos] = ((dst & 255u) << 24) | src;
        }
    }
}

__global__ __launch_bounds__(256) void kb_finalize(
    unsigned* __restrict__ bucketed, const int* __restrict__ B, int n,
    int* __restrict__ deg, int* __restrict__ rs_, float* __restrict__ dinv) {
    __shared__ unsigned ebuf[BCAP];
    __shared__ unsigned sbuf[BCAP];
    __shared__ int h[256], sc[256], cur2[256];
    int bk = blockIdx.x;
    int base = B[bk];
    int cnt = B[bk + 1] - base;
    if (cnt > BCAP) cnt = BCAP;
    for (int i = threadIdx.x; i < cnt; i += 256) ebuf[i] = bucketed[base + i];
    h[threadIdx.x] = 0;
    __syncthreads();
    for (int i = threadIdx.x; i < cnt; i += 256) atomicAdd(&h[ebuf[i] >> 24], 1);
    __syncthreads();
    int v = h[threadIdx.x];
    sc[threadIdx.x] = v;
    __syncthreads();
    for (int off = 1; off < 256; off <<= 1) {
        int t = (threadIdx.x >= off) ? sc[threadIdx.x - off] : 0;
        __syncthreads();
        sc[threadIdx.x] += t;
        __syncthreads();
    }
    int excl = sc[threadIdx.x] - v;
    int node = bk * 256 + (int)threadIdx.x;
    if (node < n) {
        deg[node] = v;
        rs_[node] = base + excl;
        dinv[node] = 1.0f / fmaxf((float)v, 1.0f);
    }
    cur2[threadIdx.x] = excl;
    __syncthreads();
    for (int i = threadIdx.x; i < cnt; i += 256) {
        unsigned u = ebuf[i];
        int p = atomicAdd(&cur2[u >> 24], 1);
        sbuf[p] = u & 0xFFFFFFu;
    }
    __syncthreads();
    for (int i = threadIdx.x; i < cnt; i += 256) bucketed[base + i] = sbuf[i];
}

// ---------------- prep ----------------
__global__ void k_prep(const float* __restrict__ x, unsigned* __restrict__ a2u,
                       const float* __restrict__ W1l, const float* __restrict__ W1r,
                       const float* __restrict__ W2l, const float* __restrict__ W2r,
                       bf16_t* __restrict__ Wf1, bf16_t* __restrict__ Wf2, int n) {
    int i = blockIdx.x * 256 + threadIdx.x;
    int nc = n * 64;
    if (i < nc) {
        int row = i >> 6, c2 = i & 63;
        float2 v = *(const float2*)&x[(size_t)row * 128 + c2 * 2];
        a2u[(size_t)row * 128 + 64 + c2] = pack2(v.x, v.y);
    } else if (i < nc + 65536) {
        int t = i - nc;
        int j = t & 7, l = (t >> 3) & 63, o16 = (t >> 9) & 15, k0 = t >> 13;
        int o = o16 * 16 + (l & 15);
        int k = k0 * 32 + ((l >> 4) & 3) * 8 + j;
        float v = (k < 128) ? W1l[(size_t)k * 256 + o] : W1r[(size_t)(k - 128) * 256 + o];
        Wf1[t] = f2bf(v);
    } else if (i < nc + 65536 + 32768) {
        int t = i - nc - 65536;
        int j = t & 7, l = (t >> 3) & 63, o16 = (t >> 9) & 7, k0 = t >> 12;
        int o = o16 * 16 + (l & 15);
        int k = k0 * 32 + ((l >> 4) & 3) * 8 + j;
        float v = (o < 64) ? W2l[(size_t)k * 64 + o] : W2r[(size_t)k * 64 + (o - 64)];
        Wf2[t] = f2bf(v);
    }
}

#define ACC4(u) { a0 += bf2f((bf16_t)(u).x); a1 += bf2f((bf16_t)((u).x >> 16)); \
                  a2 += bf2f((bf16_t)(u).y); a3 += bf2f((bf16_t)((u).y >> 16)); }

// ---------------- aggregation 1: half-wave uint2 gather ----------------
// a2u viewed as uint2: row = 64 uint2; m1 half = slots 0..31, x half = 32..63.
__global__ void k_agg1(unsigned* __restrict__ a2u, const int* __restrict__ rs,
                       const int* __restrict__ deg, const float* __restrict__ dinv,
                       const int* __restrict__ sorted, int n) {
    int gw = (blockIdx.x * 256 + threadIdx.x) >> 6;
    int lane = threadIdx.x & 63;
    if (gw >= n) return;
    int s = rs[gw], d = deg[gw];
    int half = lane >> 5, li = lane & 31;
    const uint2* gb = (const uint2*)a2u;
    float a0 = 0.f, a1 = 0.f, a2 = 0.f, a3 = 0.f;
    int j = 0;
    for (; j + 8 <= d; j += 8) {   // 4 independent 8B gathers in flight
        int i0 = sorted[s + j + half];
        int i1 = sorted[s + j + 2 + half];
        int i2 = sorted[s + j + 4 + half];
        int i3 = sorted[s + j + 6 + half];
        uint2 u0 = gb[(size_t)i0 * 64 + 32 + li];
        uint2 u1 = gb[(size_t)i1 * 64 + 32 + li];
        uint2 u2 = gb[(size_t)i2 * 64 + 32 + li];
        uint2 u3 = gb[(size_t)i3 * 64 + 32 + li];
        ACC4(u0) ACC4(u1) ACC4(u2) ACC4(u3)
    }
    for (; j < d; j += 2) {
        int e = j + half;
        int idx = sorted[s + (e < d ? e : d - 1)];
        uint2 u = gb[(size_t)idx * 64 + 32 + li];
        if (e < d) ACC4(u)
    }
    a0 += __shfl_xor(a0, 32); a1 += __shfl_xor(a1, 32);
    a2 += __shfl_xor(a2, 32); a3 += __shfl_xor(a3, 32);
    if (half == 0) {
        float dv = dinv[gw];
        uint2 o;
        o.x = pack2(a0 * dv, a1 * dv);
        o.y = pack2(a2 * dv, a3 * dv);
        ((uint2*)a2u)[(size_t)gw * 64 + li] = o;
    }
}

// ---------------- fused MFMA MLP ----------------
__global__ __launch_bounds__(256) void k_mlp(
    const bf16_t* __restrict__ a2, const bf16_t* __restrict__ Wf1,
    const bf16_t* __restrict__ Wf2, const float* __restrict__ b1,
    bf16_t* __restrict__ g, bf16_t* __restrict__ rbuf, int n) {
    __shared__ bf16_t sh[16384];   // 32KB, chunk c (16B) = (k0*4+rt)*64+lane

    int tid = threadIdx.x;
    int wave = tid >> 6, lane = tid & 63;
    int brow = blockIdx.x * 64;
    int c15 = lane & 15, rl4 = (lane >> 4) * 4;

    {
        int r = brow + ((tid >> 6) << 4) + (tid & 15);
        if (r > n - 1) r = n - 1;
        const bf16_t* src = a2 + (size_t)r * 256 + ((tid >> 4) & 3) * 8;
        short8* dst = (short8*)sh;
#pragma unroll
        for (int i = 0; i < 8; ++i)
            dst[i * 256 + tid] = *(const short8*)(src + i * 32);
    }

    float bb[4];
#pragma unroll
    for (int nt = 0; nt < 4; ++nt) bb[nt] = b1[wave * 64 + nt * 16 + c15];

    __syncthreads();

    f32x4 acc[4][4];
#pragma unroll
    for (int rt = 0; rt < 4; ++rt)
#pragma unroll
        for (int nt = 0; nt < 4; ++nt) acc[rt][nt] = (f32x4){0.f, 0.f, 0.f, 0.f};

#pragma unroll
    for (int k0 = 0; k0 < 8; ++k0) {
        short8 af[4];
#pragma unroll
        for (int rt = 0; rt < 4; ++rt)
            af[rt] = ((const short8*)sh)[(k0 * 4 + rt) * 64 + lane];
#pragma unroll
        for (int nt = 0; nt < 4; ++nt) {
            short8 bf = *(const short8*)(Wf1 + ((size_t)((k0 * 16 + wave * 4 + nt) * 64 + lane)) * 8);
#pragma unroll
            for (int rt = 0; rt < 4; ++rt)
                acc[rt][nt] = __builtin_amdgcn_mfma_f32_16x16x32_bf16(af[rt], bf, acc[rt][nt], 0, 0, 0);
        }
    }
    __syncthreads();

#pragma unroll
    for (int nt = 0; nt < 4; ++nt) {
        int kcol = wave * 64 + nt * 16 + c15;
        int k0h = kcol >> 5, kslot = (kcol >> 3) & 3, jh = kcol & 7;
#pragma unroll
        for (int rt = 0; rt < 4; ++rt)
#pragma unroll
            for (int r = 0; r < 4; ++r) {
                float v = acc[rt][nt][r] + bb[nt];
                int lane_p = (rl4 + r) | (kslot << 4);
                sh[((k0h * 4 + rt) * 64 + lane_p) * 8 + jh] = f2bf(v > 0.f ? v : 0.f);
            }
    }
    __syncthreads();

    f32x4 acc2[4][2];
#pragma unroll
    for (int rt = 0; rt < 4; ++rt)
#pragma unroll
        for (int nt = 0; nt < 2; ++nt) acc2[rt][nt] = (f32x4){0.f, 0.f, 0.f, 0.f};

#pragma unroll
    for (int k0 = 0; k0 < 8; ++k0) {
        short8 af[4];
#pragma unroll
        for (int rt = 0; rt < 4; ++rt)
            af[rt] = ((const short8*)sh)[(k0 * 4 + rt) * 64 + lane];
#pragma unroll
        for (int nt = 0; nt < 2; ++nt) {
            short8 bf = *(const short8*)(Wf2 + ((size_t)((k0 * 8 + wave * 2 + nt) * 64 + lane)) * 8);
#pragma unroll
            for (int rt = 0; rt < 4; ++rt)
                acc2[rt][nt] = __builtin_amdgcn_mfma_f32_16x16x32_bf16(af[rt], bf, acc2[rt][nt], 0, 0, 0);
        }
    }

#pragma unroll
    for (int nt = 0; nt < 2; ++nt) {
        int col = wave * 32 + nt * 16 + c15;
#pragma unroll
        for (int rt = 0; rt < 4; ++rt)
#pragma unroll
            for (int r = 0; r < 4; ++r) {
                int row = brow + rt * 16 + rl4 + r;
                if (row < n) {
                    float v = acc2[rt][nt][r];
                    if (col < 64) g[(size_t)row * 64 + col] = f2bf(v);
                    else          rbuf[(size_t)row * 64 + (col - 64)] = f2bf(v);
                }
            }
    }
}

// ---------------- aggregation 2 + log_softmax: quarter-wave uint2 gather ----
// g row = 16 uint2 (64 bf16). Quarter q handles edge j+q; lane li covers cols
// 4li..4li+3. Combine quarters by shfl_xor(16/32); float4 out stores.
__global__ void k_agg2_final(const bf16_t* __restrict__ g, const bf16_t* __restrict__ rbuf,
                             const int* __restrict__ rs, const int* __restrict__ deg,
                             const float* __restrict__ dinv, const int* __restrict__ sorted,
                             const float* __restrict__ b2, int n, float* __restrict__ out) {
    int gw = (blockIdx.x * 256 + threadIdx.x) >> 6;
    int lane = threadIdx.x & 63;
    if (gw >= n) return;
    int s = rs[gw], d = deg[gw];
    int q = lane >> 4, li = lane & 15;
    const uint2* gb = (const uint2*)g;
    float a0 = 0.f, a1 = 0.f, a2 = 0.f, a3 = 0.f;
    int j = 0;
    for (; j + 16 <= d; j += 16) {   // 4 independent 8B gathers in flight
        int i0 = sorted[s + j + q];
        int i1 = sorted[s + j + 4 + q];
        int i2 = sorted[s + j + 8 + q];
        int i3 = sorted[s + j + 12 + q];
        uint2 u0 = gb[(size_t)i0 * 16 + li];
        uint2 u1 = gb[(size_t)i1 * 16 + li];
        uint2 u2 = gb[(size_t)i2 * 16 + li];
        uint2 u3 = gb[(size_t)i3 * 16 + li];
        ACC4(u0) ACC4(u1) ACC4(u2) ACC4(u3)
    }
    for (; j < d; j += 4) {
        int e = j + q;
        int idx = sorted[s + (e < d ? e : d - 1)];
        uint2 u = gb[(size_t)idx * 16 + li];
        if (e < d) ACC4(u)
    }
    a0 += __shfl_xor(a0, 16); a0 += __shfl_xor(a0, 32);
    a1 += __shfl_xor(a1, 16); a1 += __shfl_xor(a1, 32);
    a2 += __shfl_xor(a2, 16); a2 += __shfl_xor(a2, 32);
    a3 += __shfl_xor(a3, 16); a3 += __shfl_xor(a3, 32);

    float dv = dinv[gw];
    uint2 ur = ((const uint2*)rbuf)[(size_t)gw * 16 + li];
    float4 bv = ((const float4*)b2)[li];
    float o0 = a0 * dv + bf2f((bf16_t)ur.x) + bv.x;
    float o1 = a1 * dv + bf2f((bf16_t)(ur.x >> 16)) + bv.y;
    float o2 = a2 * dv + bf2f((bf16_t)ur.y) + bv.z;
    float o3 = a3 * dv + bf2f((bf16_t)(ur.y >> 16)) + bv.w;

    float m = fmaxf(fmaxf(o0, o1), fmaxf(o2, o3));
#pragma unroll
    for (int off = 1; off < 16; off <<= 1) m = fmaxf(m, __shfl_xor(m, off));
    float ssum = expf(o0 - m) + expf(o1 - m) + expf(o2 - m) + expf(o3 - m);
#pragma unroll
    for (int off = 1; off < 16; off <<= 1) ssum += __shfl_xor(ssum, off);
    float lg = m + logf(ssum);
    if (q == 0) {
        float4 o; o.x = o0 - lg; o.y = o1 - lg; o.z = o2 - lg; o.w = o3 - lg;
        ((float4*)out)[(size_t)gw * 16 + li] = o;
    }
}

extern "C" void kernel_launch(void* const* d_in, const int* in_sizes, int n_in,
                              void* d_out, int out_size, void* d_ws, size_t ws_size,
                              hipStream_t stream) {
    const float* x   = (const float*)d_in[0];
    const int*   ei  = (const int*)d_in[1];
    const float* W1l = (const float*)d_in[2];
    const float* W1r = (const float*)d_in[3];
    const float* b1  = (const float*)d_in[4];
    const float* W2l = (const float*)d_in[5];
    const float* W2r = (const float*)d_in[6];
    const float* b2  = (const float*)d_in[7];
    float* out = (float*)d_out;

    const int N = in_sizes[0] / 128;
    const int E = in_sizes[1] / 2;
    const int nbk = (N + 255) >> 8;
    const int chunk = (E + NBLK - 1) / NBLK;

    char* ws = (char*)d_ws;
    size_t off = 0;
    int*    deg  = (int*)(ws + off);    off += (size_t)N * 4;
    int*    rs   = (int*)(ws + off);    off += (size_t)N * 4;
    float*  dinv = (float*)(ws + off);  off += (size_t)N * 4;
    int*    C    = (int*)(ws + off);    off += (size_t)NBLK * nbk * 4;
    int*    T    = (int*)(ws + off);    off += 2048;
    int*    B    = (int*)(ws + off);    off += 2048;
    bf16_t* Wf1  = (bf16_t*)(ws + off); off += 65536 * 2;
    bf16_t* Wf2  = (bf16_t*)(ws + off); off += 32768 * 2;
    int*    sorted = (int*)(ws + off);  off += (size_t)E * 4;
    bf16_t* a2   = (bf16_t*)(ws + off); off += (size_t)N * 256 * 2;
    bf16_t* g    = (bf16_t*)(ws + off); off += (size_t)N * 64 * 2;
    bf16_t* rbuf = (bf16_t*)(ws + off); off += (size_t)N * 64 * 2;

    kb_hist    <<<NBLK, 256, 0, stream>>>(ei, E, chunk, N, nbk, C);
    kb_scanA   <<<nbk, 256, 0, stream>>>(C, nbk, T);
    kb_scanB   <<<1, 512, 0, stream>>>(T, nbk, B);
    kb_scatter <<<NBLK, 256, 0, stream>>>(ei, E, chunk, N, nbk, C, B, (unsigned*)sorted);
    kb_finalize<<<nbk, 256, 0, stream>>>((unsigned*)sorted, B, N, deg, rs, dinv);

    k_prep  <<<(N * 64 + 98304 + 255) / 256, 256, 0, stream>>>(x, (unsigned*)a2,
                                                               W1l, W1r, W2l, W2r, Wf1, Wf2, N);
    k_agg1  <<<(N * 64 + 255) / 256, 256, 0, stream>>>((unsigned*)a2, rs, deg, dinv, sorted, N);
    k_mlp   <<<(N + 63) / 64, 256, 0, stream>>>(a2, Wf1, Wf2, b1, g, rbuf, N);
    k_agg2_final<<<(N * 64 + 255) / 256, 256, 0, stream>>>(g, rbuf, rs, deg, dinv, sorted, b2, N, out);
}